// Round 11
// baseline (446.517 us; speedup 1.0000x reference)
//
#include <hip/hip_runtime.h>
#include <math.h>

// Problem constants (from setup_inputs)
#define T_TOK 2048   // B*S
#define D_DIM 1024   // hidden
#define E_NUM 8      // experts
#define DFS   2048   // shared ffn
#define DFE   512    // expert ffn

// GEMM tile: 64x64x32, 4 waves, each wave 32x32 (acc[2][2]).
// LDS-FREE: MFMA fragments loaded directly from global (B^T layout makes
// each lane's fragment 8 contiguous bf16). No barriers in the K-loop.
#define BM 64
#define BN 64
#define BK 32

typedef short short8 __attribute__((ext_vector_type(8)));
typedef float floatx4 __attribute__((ext_vector_type(4)));
typedef unsigned short ushort;

// float -> bf16 (RNE)
__device__ __forceinline__ ushort f2b(float f) {
  union { float f; unsigned u; } v; v.f = f;
  unsigned r = (v.u + 0x7fffu + ((v.u >> 16) & 1u)) >> 16;
  return (ushort)r;
}

__device__ __forceinline__ float silu_mul(float g, float u) {
  return (g / (1.f + __expf(-g))) * u;
}

// ---------------------------------------------------------------------------
// mega_prep: router (+x->bf16), fp32 weight cvt, int32 quant cvt.
// grid.x = 512 + 3072 + 6144 = 9728, block 256.
// ---------------------------------------------------------------------------
__global__ __launch_bounds__(256) void mega_prep(
    const float* __restrict__ x, const float* __restrict__ rw,
    const float* __restrict__ alpha,
    const float* __restrict__ sg, const float* __restrict__ su,
    const float* __restrict__ sd,
    const int* __restrict__ gq, const int* __restrict__ uq,
    const int* __restrict__ dq,
    int* __restrict__ choice, float2* __restrict__ cpair,
    float* __restrict__ csum, ushort* __restrict__ xb,
    ushort* __restrict__ sgb, ushort* __restrict__ subb,
    ushort* __restrict__ sdb,
    ushort* __restrict__ gqb, ushort* __restrict__ uqb,
    ushort* __restrict__ dqb) {
  const int b = blockIdx.x;
  const int tid = threadIdx.x;
  if (b < 512) {
    __shared__ float xs[4 * D_DIM];
    const size_t base = (size_t)b * 4 * D_DIM;
#pragma unroll
    for (int j = 0; j < 4; ++j) {
      const int idx = j * 1024 + tid * 4;
      float4 v = *(const float4*)(x + base + idx);
      *(float4*)&xs[idx] = v;
      union { ushort u[4]; uint2 p; } o;
      o.u[0] = f2b(v.x); o.u[1] = f2b(v.y); o.u[2] = f2b(v.z); o.u[3] = f2b(v.w);
      *(uint2*)(xb + base + idx) = o.p;
    }
    __syncthreads();
    const int w = tid >> 6, l = tid & 63;
    const int t = b * 4 + w;
    const int e = l >> 3, sub = l & 7;
    const float* wr = rw + e * D_DIM;
    float acc = 0.f;
#pragma unroll
    for (int k = 0; k < 32; ++k) {
      const int d = k * 32 + sub * 4;
      float4 xv = *(const float4*)&xs[w * D_DIM + d];
      float4 wv = *(const float4*)(wr + d);
      acc += xv.x * wv.x + xv.y * wv.y + xv.z * wv.z + xv.w * wv.w;
    }
    acc += __shfl_xor(acc, 1);
    acc += __shfl_xor(acc, 2);
    acc += __shfl_xor(acc, 4);
    float lg[8];
#pragma unroll
    for (int i = 0; i < 8; ++i) lg[i] = __shfl(acc, i * 8);
    if (l == 0) {
      int i0 = 0; float v0 = lg[0];
#pragma unroll
      for (int i = 1; i < E_NUM; ++i) if (lg[i] > v0) { v0 = lg[i]; i0 = i; }
      int i1 = -1; float v1 = -1e30f;
#pragma unroll
      for (int i = 0; i < E_NUM; ++i) {
        if (i == i0) continue;
        if (lg[i] > v1) { v1 = lg[i]; i1 = i; }
      }
      float w0 = 1.f / (1.f + __expf(v1 - v0));
      float w1 = 1.f - w0;
      float c0 = w0 * alpha[i0];
      float c1 = w1 * alpha[i1];
      csum[t] = c0 + c1;
      choice[t] = i0 | (i1 << 4);
      cpair[t] = make_float2(c0, c1);
    }
  } else if (b < 512 + 3072) {
    const int bb = b - 512;
    const int which = bb >> 10;
    const float* src; ushort* dst;
    if (which == 0) { src = sg; dst = sgb; }
    else if (which == 1) { src = su; dst = subb; }
    else { src = sd; dst = sdb; }
    const size_t i = (size_t)(bb & 1023) * 256 + tid;
    const float4* sp = (const float4*)src;
    float4 a = sp[2 * i], c = sp[2 * i + 1];
    union { ushort u[8]; uint4 v; } o;
    o.u[0] = f2b(a.x); o.u[1] = f2b(a.y); o.u[2] = f2b(a.z); o.u[3] = f2b(a.w);
    o.u[4] = f2b(c.x); o.u[5] = f2b(c.y); o.u[6] = f2b(c.z); o.u[7] = f2b(c.w);
    ((uint4*)dst)[i] = o.v;
  } else {
    const int bb = b - 3584;
    const int which = bb >> 11;
    const int* src; ushort* dst;
    if (which == 0) { src = gq; dst = gqb; }
    else if (which == 1) { src = uq; dst = uqb; }
    else { src = dq; dst = dqb; }
    const size_t i = (size_t)(bb & 2047) * 256 + tid;
    const int4* sp = (const int4*)src;
    int4 a = sp[2 * i], c = sp[2 * i + 1];
    union { ushort u[8]; uint4 v; } o;
    o.u[0] = f2b((float)a.x); o.u[1] = f2b((float)a.y);
    o.u[2] = f2b((float)a.z); o.u[3] = f2b((float)a.w);
    o.u[4] = f2b((float)c.x); o.u[5] = f2b((float)c.y);
    o.u[6] = f2b((float)c.z); o.u[7] = f2b((float)c.w);
    ((uint4*)dst)[i] = o.v;
  }
}

// ---------------------------------------------------------------------------
// build_lists: single block; counts cnt[e], bases cnt[8+e], inverse map ass.
// ---------------------------------------------------------------------------
__global__ __launch_bounds__(1024) void build_lists(
    const int* __restrict__ choice, int* __restrict__ cnt,
    int* __restrict__ tok_list, uint2* __restrict__ ass) {
  __shared__ int lcnt[E_NUM];
  __shared__ int lbase[E_NUM];
  const int tid = threadIdx.x;
  if (tid < E_NUM) lcnt[tid] = 0;
  __syncthreads();
  uint2 tmp[T_TOK / 1024];
#pragma unroll
  for (int r = 0; r < T_TOK / 1024; ++r) {
    const int t = r * 1024 + tid;
    const int ch = choice[t];
    const int i0 = ch & 15, i1 = ch >> 4;
    const int p0 = atomicAdd(&lcnt[i0], 1);
    tok_list[i0 * T_TOK + p0] = t;
    const int p1 = atomicAdd(&lcnt[i1], 1);
    tok_list[i1 * T_TOK + p1] = t;
    tmp[r] = make_uint2((unsigned)((i0 << 16) | p0), (unsigned)((i1 << 16) | p1));
  }
  __syncthreads();
  if (tid < E_NUM) {
    int b = 0;
    for (int i = 0; i < tid; ++i) b += lcnt[i];
    lbase[tid] = b;
    cnt[tid] = lcnt[tid];
    cnt[8 + tid] = b;
  }
  __syncthreads();
#pragma unroll
  for (int r = 0; r < T_TOK / 1024; ++r) {
    const int t = r * 1024 + tid;
    const uint2 v = tmp[r];
    ass[t] = make_uint2(lbase[v.x >> 16] + (v.x & 0xffffu),
                        lbase[v.y >> 16] + (v.y & 0xffffu));
  }
}

// ---------------------------------------------------------------------------
// LDS-free GEMMs.  Wave (wr,wc) computes rows m0+wr*32+{0,16}+rb,
// cols n0+wc*32+{0,16}+rb.  Fragment = 8 contiguous bf16 at (row, k0+kc).
// ---------------------------------------------------------------------------

// Shared gate+up:  sbuf = silu(x@Wg^T) * (x@Wu^T), bf16.  grid (32, 32).
__global__ __launch_bounds__(256) void mfma_shared_gateup(
    const ushort* __restrict__ xb, const ushort* __restrict__ wg,
    const ushort* __restrict__ wu, ushort* __restrict__ sbuf) {
  const int tid = threadIdx.x;
  const int wave = tid >> 6, lane = tid & 63;
  const int wr = wave >> 1, wc = wave & 1;
  const int m0 = blockIdx.y * BM, n0 = blockIdx.x * BN;
  const int rb = lane & 15;
  const int kc = (lane >> 4) * 8;
  const int K = D_DIM;

  const ushort* ar0 = xb + (size_t)(m0 + wr * 32 + rb) * K + kc;
  const ushort* ar1 = ar0 + (size_t)16 * K;
  const ushort* gr0 = wg + (size_t)(n0 + wc * 32 + rb) * K + kc;
  const ushort* gr1 = gr0 + (size_t)16 * K;
  const ushort* ur0 = wu + (size_t)(n0 + wc * 32 + rb) * K + kc;
  const ushort* ur1 = ur0 + (size_t)16 * K;

  floatx4 accg[2][2], accu[2][2];
#pragma unroll
  for (int i = 0; i < 2; ++i)
#pragma unroll
    for (int j = 0; j < 2; ++j) { accg[i][j] = (floatx4)(0.f); accu[i][j] = (floatx4)(0.f); }

#pragma unroll 4
  for (int k0 = 0; k0 < K; k0 += BK) {
    short8 af[2], gf[2], uf[2];
    af[0] = *(const short8*)(ar0 + k0);
    af[1] = *(const short8*)(ar1 + k0);
    gf[0] = *(const short8*)(gr0 + k0);
    gf[1] = *(const short8*)(gr1 + k0);
    uf[0] = *(const short8*)(ur0 + k0);
    uf[1] = *(const short8*)(ur1 + k0);
#pragma unroll
    for (int mt = 0; mt < 2; ++mt)
#pragma unroll
      for (int nt = 0; nt < 2; ++nt) {
        accg[mt][nt] = __builtin_amdgcn_mfma_f32_16x16x32_bf16(af[mt], gf[nt], accg[mt][nt], 0, 0, 0);
        accu[mt][nt] = __builtin_amdgcn_mfma_f32_16x16x32_bf16(af[mt], uf[nt], accu[mt][nt], 0, 0, 0);
      }
  }
#pragma unroll
  for (int mt = 0; mt < 2; ++mt)
#pragma unroll
    for (int nt = 0; nt < 2; ++nt) {
      const int col = n0 + wc * 32 + nt * 16 + rb;
#pragma unroll
      for (int r = 0; r < 4; ++r) {
        const int row = m0 + wr * 32 + mt * 16 + (lane >> 4) * 4 + r;
        float s = silu_mul(accg[mt][nt][r], accu[mt][nt][r]);
        sbuf[(size_t)row * DFS + col] = f2b(s);
      }
    }
}

// Shared down (split-K x2):  shd_z[t,d] = partial, plain store.  grid (16,32,2).
__global__ __launch_bounds__(256) void mfma_shared_down(
    const ushort* __restrict__ sb, const ushort* __restrict__ wd,
    float* __restrict__ shd0, float* __restrict__ shd1) {
  const int tid = threadIdx.x;
  const int wave = tid >> 6, lane = tid & 63;
  const int wr = wave >> 1, wc = wave & 1;
  const int m0 = blockIdx.y * BM, n0 = blockIdx.x * BN;
  const int kb = blockIdx.z * (DFS / 2);
  float* dst = blockIdx.z ? shd1 : shd0;
  const int rb = lane & 15;
  const int kc = (lane >> 4) * 8;

  const ushort* ar0 = sb + (size_t)(m0 + wr * 32 + rb) * DFS + kb + kc;
  const ushort* ar1 = ar0 + (size_t)16 * DFS;
  const ushort* br0 = wd + (size_t)(n0 + wc * 32 + rb) * DFS + kb + kc;
  const ushort* br1 = br0 + (size_t)16 * DFS;

  floatx4 acc[2][2];
#pragma unroll
  for (int i = 0; i < 2; ++i)
#pragma unroll
    for (int j = 0; j < 2; ++j) acc[i][j] = (floatx4)(0.f);

#pragma unroll 4
  for (int k0 = 0; k0 < DFS / 2; k0 += BK) {
    short8 af[2], bf[2];
    af[0] = *(const short8*)(ar0 + k0);
    af[1] = *(const short8*)(ar1 + k0);
    bf[0] = *(const short8*)(br0 + k0);
    bf[1] = *(const short8*)(br1 + k0);
#pragma unroll
    for (int mt = 0; mt < 2; ++mt)
#pragma unroll
      for (int nt = 0; nt < 2; ++nt)
        acc[mt][nt] = __builtin_amdgcn_mfma_f32_16x16x32_bf16(af[mt], bf[nt], acc[mt][nt], 0, 0, 0);
  }
#pragma unroll
  for (int mt = 0; mt < 2; ++mt)
#pragma unroll
    for (int nt = 0; nt < 2; ++nt) {
      const int col = n0 + wc * 32 + nt * 16 + rb;
#pragma unroll
      for (int r = 0; r < 4; ++r) {
        const int row = m0 + wr * 32 + mt * 16 + (lane >> 4) * 4 + r;
        dst[(size_t)row * D_DIM + col] = acc[mt][nt][r];
      }
    }
}

// Expert gate+up (gathered):  act[base[e]+slot, f] = silu(g*gs)*(u*us), bf16.
// grid (8,32,8).
__global__ __launch_bounds__(256) void mfma_expert_gateup(
    const ushort* __restrict__ xb, const ushort* __restrict__ gq,
    const ushort* __restrict__ uq, const float* __restrict__ gate_s,
    const float* __restrict__ up_s, const int* __restrict__ cnt,
    const int* __restrict__ tok_list, ushort* __restrict__ act) {
  const int e = blockIdx.z;
  const int ce = cnt[e];
  const int m0 = blockIdx.y * BM;
  if (m0 >= ce) return;
  const int ebase = cnt[8 + e];
  const int n0 = blockIdx.x * BN;
  const int tid = threadIdx.x;
  const int wave = tid >> 6, lane = tid & 63;
  const int wr = wave >> 1, wc = wave & 1;
  const int rb = lane & 15;
  const int kc = (lane >> 4) * 8;
  const int K = D_DIM;

  const int r0 = m0 + wr * 32 + rb;
  const int r1 = r0 + 16;
  const int tk0 = (r0 < ce) ? tok_list[e * T_TOK + r0] : 0;
  const int tk1 = (r1 < ce) ? tok_list[e * T_TOK + r1] : 0;
  const ushort* ar0 = xb + (size_t)tk0 * K + kc;
  const ushort* ar1 = xb + (size_t)tk1 * K + kc;
  const ushort* gqe = gq + (size_t)e * DFE * D_DIM;
  const ushort* uqe = uq + (size_t)e * DFE * D_DIM;
  const ushort* gr0 = gqe + (size_t)(n0 + wc * 32 + rb) * K + kc;
  const ushort* gr1 = gr0 + (size_t)16 * K;
  const ushort* ur0 = uqe + (size_t)(n0 + wc * 32 + rb) * K + kc;
  const ushort* ur1 = ur0 + (size_t)16 * K;

  floatx4 accg[2][2], accu[2][2];
#pragma unroll
  for (int i = 0; i < 2; ++i)
#pragma unroll
    for (int j = 0; j < 2; ++j) { accg[i][j] = (floatx4)(0.f); accu[i][j] = (floatx4)(0.f); }

#pragma unroll 4
  for (int k0 = 0; k0 < K; k0 += BK) {
    short8 af[2], gf[2], uf[2];
    af[0] = *(const short8*)(ar0 + k0);
    af[1] = *(const short8*)(ar1 + k0);
    gf[0] = *(const short8*)(gr0 + k0);
    gf[1] = *(const short8*)(gr1 + k0);
    uf[0] = *(const short8*)(ur0 + k0);
    uf[1] = *(const short8*)(ur1 + k0);
#pragma unroll
    for (int mt = 0; mt < 2; ++mt)
#pragma unroll
      for (int nt = 0; nt < 2; ++nt) {
        accg[mt][nt] = __builtin_amdgcn_mfma_f32_16x16x32_bf16(af[mt], gf[nt], accg[mt][nt], 0, 0, 0);
        accu[mt][nt] = __builtin_amdgcn_mfma_f32_16x16x32_bf16(af[mt], uf[nt], accu[mt][nt], 0, 0, 0);
      }
  }
#pragma unroll
  for (int mt = 0; mt < 2; ++mt)
#pragma unroll
    for (int nt = 0; nt < 2; ++nt) {
      const int col = n0 + wc * 32 + nt * 16 + rb;
      const float gsc = gate_s[e * DFE + col];
      const float usc = up_s[e * DFE + col];
#pragma unroll
      for (int r = 0; r < 4; ++r) {
        const int slot = m0 + wr * 32 + mt * 16 + (lane >> 4) * 4 + r;
        if (slot < ce) {   // compacted layout: must not stomp next expert
          float s = silu_mul(accg[mt][nt][r] * gsc, accu[mt][nt][r] * usc);
          act[(size_t)(ebase + slot) * DFE + col] = f2b(s);
        }
      }
    }
}

// Expert down:  pbuf[base[e]+slot, d] = partial * down_s[d], plain store.
// grid (16,32,8).
__global__ __launch_bounds__(256) void mfma_expert_down(
    const ushort* __restrict__ act, const ushort* __restrict__ dq,
    const float* __restrict__ down_s, const int* __restrict__ cnt,
    float* __restrict__ pbuf) {
  const int e = blockIdx.z;
  const int ce = cnt[e];
  const int m0 = blockIdx.y * BM;
  if (m0 >= ce) return;
  const int ebase = cnt[8 + e];
  const int n0 = blockIdx.x * BN;
  const int tid = threadIdx.x;
  const int wave = tid >> 6, lane = tid & 63;
  const int wr = wave >> 1, wc = wave & 1;
  const int rb = lane & 15;
  const int kc = (lane >> 4) * 8;

  // A rows: compacted act rows (reads past ce feed only discarded rows;
  // buffer has slack after).
  const ushort* ar0 = act + (size_t)(ebase + m0 + wr * 32 + rb) * DFE + kc;
  const ushort* ar1 = ar0 + (size_t)16 * DFE;
  const ushort* br0 = dq + (size_t)e * D_DIM * DFE + (size_t)(n0 + wc * 32 + rb) * DFE + kc;
  const ushort* br1 = br0 + (size_t)16 * DFE;

  floatx4 acc[2][2];
#pragma unroll
  for (int i = 0; i < 2; ++i)
#pragma unroll
    for (int j = 0; j < 2; ++j) acc[i][j] = (floatx4)(0.f);

#pragma unroll 4
  for (int k0 = 0; k0 < DFE; k0 += BK) {
    short8 af[2], bf[2];
    af[0] = *(const short8*)(ar0 + k0);
    af[1] = *(const short8*)(ar1 + k0);
    bf[0] = *(const short8*)(br0 + k0);
    bf[1] = *(const short8*)(br1 + k0);
#pragma unroll
    for (int mt = 0; mt < 2; ++mt)
#pragma unroll
      for (int nt = 0; nt < 2; ++nt)
        acc[mt][nt] = __builtin_amdgcn_mfma_f32_16x16x32_bf16(af[mt], bf[nt], acc[mt][nt], 0, 0, 0);
  }
#pragma unroll
  for (int mt = 0; mt < 2; ++mt)
#pragma unroll
    for (int nt = 0; nt < 2; ++nt) {
      const int col = n0 + wc * 32 + nt * 16 + rb;
      const float dsc = down_s[e * D_DIM + col];
#pragma unroll
      for (int r = 0; r < 4; ++r) {
        const int slot = m0 + wr * 32 + mt * 16 + (lane >> 4) * 4 + r;
        if (slot < ce)
          pbuf[(size_t)(ebase + slot) * D_DIM + col] = acc[mt][nt][r] * dsc;
      }
    }
}

// ---------------------------------------------------------------------------
// combine: out[t] = (1-csum)*(shd0+shd1) + c0*pbuf[a0] + c1*pbuf[a1]
// ---------------------------------------------------------------------------
__global__ __launch_bounds__(256) void combine_kernel(
    const float* __restrict__ shd0, const float* __restrict__ shd1,
    const float* __restrict__ pbuf, const float* __restrict__ csum,
    const float2* __restrict__ cpair, const uint2* __restrict__ ass,
    float* __restrict__ out) {
  const int t = blockIdx.x;
  const int c4 = threadIdx.x * 4;
  const float cs = 1.f - csum[t];
  const float2 cp = cpair[t];
  const uint2 a = ass[t];
  const size_t idx = (size_t)t * D_DIM + c4;
  float4 s0 = *(const float4*)(shd0 + idx);
  float4 s1 = *(const float4*)(shd1 + idx);
  float4 e0 = *(const float4*)(pbuf + (size_t)a.x * D_DIM + c4);
  float4 e1 = *(const float4*)(pbuf + (size_t)a.y * D_DIM + c4);
  float4 o;
  o.x = cs * (s0.x + s1.x) + cp.x * e0.x + cp.y * e1.x;
  o.y = cs * (s0.y + s1.y) + cp.x * e0.y + cp.y * e1.y;
  o.z = cs * (s0.z + s1.z) + cp.x * e0.z + cp.y * e1.z;
  o.w = cs * (s0.w + s1.w) + cp.x * e0.w + cp.y * e1.w;
  *(float4*)(out + idx) = o;
}

// ---------------------------------------------------------------------------
extern "C" void kernel_launch(void* const* d_in, const int* in_sizes, int n_in,
                              void* d_out, int out_size, void* d_ws, size_t ws_size,
                              hipStream_t stream) {
  const float* x         = (const float*)d_in[0];
  const float* rw        = (const float*)d_in[1];
  const float* sh_gate_w = (const float*)d_in[2];
  const float* sh_up_w   = (const float*)d_in[3];
  const float* sh_down_w = (const float*)d_in[4];
  const float* gate_s    = (const float*)d_in[5];
  const float* up_s      = (const float*)d_in[6];
  const float* down_s    = (const float*)d_in[7];
  const float* alpha     = (const float*)d_in[8];
  const int*   gate_q    = (const int*)d_in[9];
  const int*   up_q      = (const int*)d_in[10];
  const int*   down_q    = (const int*)d_in[11];

  char* ws = (char*)d_ws;
  const size_t MB = 1u << 20;
  // Workspace map (61 MB total):
  int*    cnt      = (int*)ws;                 // 64 B: cnt[0..7], base[8..15]
  int*    tok_list = (int*)(ws + 1024);        // 64 KB
  float*  csum     = (float*)(ws + 66560);     // 8 KB
  int*    choice   = (int*)(ws + 74752);       // 8 KB
  float2* cpair    = (float2*)(ws + 82944);    // 16 KB
  uint2*  ass      = (uint2*)(ws + 99328);     // 16 KB
  ushort* xb      = (ushort*)(ws + 1 * MB);    // 4 MB  [2048,1024]
  ushort* sgb     = (ushort*)(ws + 5 * MB);    // 4 MB  [2048,1024]
  ushort* sub     = (ushort*)(ws + 9 * MB);    // 4 MB  [2048,1024]
  float*  shd0    = (float*)(ws + 5 * MB);     // 8 MB fp32, overlays sgb+sub
                                               // (dead after shared_gateup)
  ushort* sbuf    = (ushort*)(ws + 13 * MB);   // 8 MB  [2048,2048]
  ushort* sdb     = (ushort*)(ws + 21 * MB);   // 4 MB  [1024,2048]
  ushort* gqb     = (ushort*)(ws + 25 * MB);   // 8 MB  [8,512,1024]
  ushort* uqb     = (ushort*)(ws + 33 * MB);   // 8 MB  [8,512,1024]
  float*  pbuf    = (float*)(ws + 25 * MB);    // 16 MB [4096,1024] fp32,
                                               // overlays gqb+uqb (dead after expert_gateup)
  ushort* dqb     = (ushort*)(ws + 41 * MB);   // 8 MB  [8,1024,512]
  ushort* act     = (ushort*)(ws + 49 * MB);   // 4 MB  [4096,512] bf16 (compacted)
  float*  shd1    = (float*)(ws + 53 * MB);    // 8 MB  [2048,1024] fp32

  float* out = (float*)d_out;

  mega_prep<<<9728, 256, 0, stream>>>(
      x, rw, alpha, sh_gate_w, sh_up_w, sh_down_w, gate_q, up_q, down_q,
      choice, cpair, csum, xb, sgb, sub, sdb, gqb, uqb, dqb);
  build_lists<<<1, 1024, 0, stream>>>(choice, cnt, tok_list, ass);

  mfma_shared_gateup<<<dim3(DFS / BN, T_TOK / BM), 256, 0, stream>>>(xb, sgb, sub, sbuf);
  mfma_expert_gateup<<<dim3(DFE / BN, T_TOK / BM, E_NUM), 256, 0, stream>>>(
      xb, gqb, uqb, gate_s, up_s, cnt, tok_list, act);
  mfma_shared_down<<<dim3(D_DIM / BN, T_TOK / BM, 2), 256, 0, stream>>>(sbuf, sdb, shd0, shd1);
  mfma_expert_down<<<dim3(D_DIM / BN, T_TOK / BM, E_NUM), 256, 0, stream>>>(
      act, dqb, down_s, cnt, pbuf);
  combine_kernel<<<T_TOK, 256, 0, stream>>>(shd0, shd1, pbuf, csum, cpair, ass, out);
}

// Round 12
// 237.727 us; speedup vs baseline: 1.8783x; 1.8783x over previous
//
#include <hip/hip_runtime.h>
#include <math.h>

// Problem constants (from setup_inputs)
#define T_TOK 2048   // B*S
#define D_DIM 1024   // hidden
#define E_NUM 8      // experts
#define DFS   2048   // shared ffn
#define DFE   512    // expert ffn

// GEMM tile: 64x64, 4 waves, each wave 32x32 (acc[2][2]).
// K-loop steps by 64 = two BK=32 stages per barrier pair (6 gld16 in flight).
#define BM 64
#define BN 64
#define BK 32

typedef short short8 __attribute__((ext_vector_type(8)));
typedef float floatx4 __attribute__((ext_vector_type(4)));
typedef unsigned short ushort;

// float -> bf16 (RNE)
__device__ __forceinline__ ushort f2b(float f) {
  union { float f; unsigned u; } v; v.f = f;
  unsigned r = (v.u + 0x7fffu + ((v.u >> 16) & 1u)) >> 16;
  return (ushort)r;
}

// async global->LDS, 16B per lane. lds ptr must be wave-uniform.
__device__ __forceinline__ void gld16(const ushort* g, ushort* l) {
  __builtin_amdgcn_global_load_lds(
      (const __attribute__((address_space(1))) void*)g,
      (__attribute__((address_space(3))) void*)l,
      16, 0, 0);
}

__device__ __forceinline__ float silu_mul(float g, float u) {
  return (g / (1.f + __expf(-g))) * u;
}

// ---------------------------------------------------------------------------
// mega_prep: router (+x->bf16), fp32 weight cvt, int32 quant cvt.
// grid.x = 512 + 3072 + 6144 = 9728, block 256.
// ---------------------------------------------------------------------------
__global__ __launch_bounds__(256) void mega_prep(
    const float* __restrict__ x, const float* __restrict__ rw,
    const float* __restrict__ alpha,
    const float* __restrict__ sg, const float* __restrict__ su,
    const float* __restrict__ sd,
    const int* __restrict__ gq, const int* __restrict__ uq,
    const int* __restrict__ dq,
    int* __restrict__ choice, float2* __restrict__ cpair,
    float* __restrict__ csum, ushort* __restrict__ xb,
    ushort* __restrict__ sgb, ushort* __restrict__ subb,
    ushort* __restrict__ sdb,
    ushort* __restrict__ gqb, ushort* __restrict__ uqb,
    ushort* __restrict__ dqb) {
  const int b = blockIdx.x;
  const int tid = threadIdx.x;
  if (b < 512) {
    __shared__ float xs[4 * D_DIM];
    const size_t base = (size_t)b * 4 * D_DIM;
#pragma unroll
    for (int j = 0; j < 4; ++j) {
      const int idx = j * 1024 + tid * 4;
      float4 v = *(const float4*)(x + base + idx);
      *(float4*)&xs[idx] = v;
      union { ushort u[4]; uint2 p; } o;
      o.u[0] = f2b(v.x); o.u[1] = f2b(v.y); o.u[2] = f2b(v.z); o.u[3] = f2b(v.w);
      *(uint2*)(xb + base + idx) = o.p;
    }
    __syncthreads();
    const int w = tid >> 6, l = tid & 63;
    const int t = b * 4 + w;
    const int e = l >> 3, sub = l & 7;
    const float* wr = rw + e * D_DIM;
    float acc = 0.f;
#pragma unroll
    for (int k = 0; k < 32; ++k) {
      const int d = k * 32 + sub * 4;
      float4 xv = *(const float4*)&xs[w * D_DIM + d];
      float4 wv = *(const float4*)(wr + d);
      acc += xv.x * wv.x + xv.y * wv.y + xv.z * wv.z + xv.w * wv.w;
    }
    acc += __shfl_xor(acc, 1);
    acc += __shfl_xor(acc, 2);
    acc += __shfl_xor(acc, 4);
    float lg[8];
#pragma unroll
    for (int i = 0; i < 8; ++i) lg[i] = __shfl(acc, i * 8);
    if (l == 0) {
      int i0 = 0; float v0 = lg[0];
#pragma unroll
      for (int i = 1; i < E_NUM; ++i) if (lg[i] > v0) { v0 = lg[i]; i0 = i; }
      int i1 = -1; float v1 = -1e30f;
#pragma unroll
      for (int i = 0; i < E_NUM; ++i) {
        if (i == i0) continue;
        if (lg[i] > v1) { v1 = lg[i]; i1 = i; }
      }
      float w0 = 1.f / (1.f + __expf(v1 - v0));
      float w1 = 1.f - w0;
      float c0 = w0 * alpha[i0];
      float c1 = w1 * alpha[i1];
      csum[t] = c0 + c1;
      choice[t] = i0 | (i1 << 4);
      cpair[t] = make_float2(c0, c1);
    }
  } else if (b < 512 + 3072) {
    const int bb = b - 512;
    const int which = bb >> 10;
    const float* src; ushort* dst;
    if (which == 0) { src = sg; dst = sgb; }
    else if (which == 1) { src = su; dst = subb; }
    else { src = sd; dst = sdb; }
    const size_t i = (size_t)(bb & 1023) * 256 + tid;
    const float4* sp = (const float4*)src;
    float4 a = sp[2 * i], c = sp[2 * i + 1];
    union { ushort u[8]; uint4 v; } o;
    o.u[0] = f2b(a.x); o.u[1] = f2b(a.y); o.u[2] = f2b(a.z); o.u[3] = f2b(a.w);
    o.u[4] = f2b(c.x); o.u[5] = f2b(c.y); o.u[6] = f2b(c.z); o.u[7] = f2b(c.w);
    ((uint4*)dst)[i] = o.v;
  } else {
    const int bb = b - 3584;
    const int which = bb >> 11;
    const int* src; ushort* dst;
    if (which == 0) { src = gq; dst = gqb; }
    else if (which == 1) { src = uq; dst = uqb; }
    else { src = dq; dst = dqb; }
    const size_t i = (size_t)(bb & 2047) * 256 + tid;
    const int4* sp = (const int4*)src;
    int4 a = sp[2 * i], c = sp[2 * i + 1];
    union { ushort u[8]; uint4 v; } o;
    o.u[0] = f2b((float)a.x); o.u[1] = f2b((float)a.y);
    o.u[2] = f2b((float)a.z); o.u[3] = f2b((float)a.w);
    o.u[4] = f2b((float)c.x); o.u[5] = f2b((float)c.y);
    o.u[6] = f2b((float)c.z); o.u[7] = f2b((float)c.w);
    ((uint4*)dst)[i] = o.v;
  }
}

// ---------------------------------------------------------------------------
// build_lists: single block; counts cnt[e], bases cnt[8+e], inverse map ass.
// ---------------------------------------------------------------------------
__global__ __launch_bounds__(1024) void build_lists(
    const int* __restrict__ choice, int* __restrict__ cnt,
    int* __restrict__ tok_list, uint2* __restrict__ ass) {
  __shared__ int lcnt[E_NUM];
  __shared__ int lbase[E_NUM];
  const int tid = threadIdx.x;
  if (tid < E_NUM) lcnt[tid] = 0;
  __syncthreads();
  uint2 tmp[T_TOK / 1024];
#pragma unroll
  for (int r = 0; r < T_TOK / 1024; ++r) {
    const int t = r * 1024 + tid;
    const int ch = choice[t];
    const int i0 = ch & 15, i1 = ch >> 4;
    const int p0 = atomicAdd(&lcnt[i0], 1);
    tok_list[i0 * T_TOK + p0] = t;
    const int p1 = atomicAdd(&lcnt[i1], 1);
    tok_list[i1 * T_TOK + p1] = t;
    tmp[r] = make_uint2((unsigned)((i0 << 16) | p0), (unsigned)((i1 << 16) | p1));
  }
  __syncthreads();
  if (tid < E_NUM) {
    int b = 0;
    for (int i = 0; i < tid; ++i) b += lcnt[i];
    lbase[tid] = b;
    cnt[tid] = lcnt[tid];
    cnt[8 + tid] = b;
  }
  __syncthreads();
#pragma unroll
  for (int r = 0; r < T_TOK / 1024; ++r) {
    const int t = r * 1024 + tid;
    const uint2 v = tmp[r];
    ass[t] = make_uint2(lbase[v.x >> 16] + (v.x & 0xffffu),
                        lbase[v.y >> 16] + (v.y & 0xffffu));
  }
}

// ---------------------------------------------------------------------------
// GEMMs: 64x64 tile, K-step 64 (two BK=32 sub-stages per barrier pair).
// Wave w stages rows [w*16, w*16+16) of each sub-tile (1 gld16 each).
// ---------------------------------------------------------------------------

// Shared gate+up:  sbuf = silu(x@Wg^T) * (x@Wu^T), bf16.  grid (32, 32).
__global__ __launch_bounds__(256) void mfma_shared_gateup(
    const ushort* __restrict__ xb, const ushort* __restrict__ wg,
    const ushort* __restrict__ wu, ushort* __restrict__ sbuf) {
  __shared__ ushort As[2 * BM * BK];
  __shared__ ushort Bg[2 * BN * BK];
  __shared__ ushort Bu[2 * BN * BK];
  const int tid = threadIdx.x;
  const int wave = tid >> 6, lane = tid & 63;
  const int wr = wave >> 1, wc = wave & 1;
  const int m0 = blockIdx.y * BM, n0 = blockIdx.x * BN;
  const int srow = lane >> 2;
  const int scol = (lane & 3) * 8;
  const int K = D_DIM;

  const ushort* a0 = xb + (size_t)(m0 + wave * 16 + srow) * K + scol;
  const ushort* g0 = wg + (size_t)(n0 + wave * 16 + srow) * K + scol;
  const ushort* u0 = wu + (size_t)(n0 + wave * 16 + srow) * K + scol;
  ushort* lA0 = &As[(wave * 16) * BK];  ushort* lA1 = lA0 + BM * BK;
  ushort* lG0 = &Bg[(wave * 16) * BK];  ushort* lG1 = lG0 + BN * BK;
  ushort* lU0 = &Bu[(wave * 16) * BK];  ushort* lU1 = lU0 + BN * BK;

  floatx4 accg[2][2], accu[2][2];
#pragma unroll
  for (int i = 0; i < 2; ++i)
#pragma unroll
    for (int j = 0; j < 2; ++j) { accg[i][j] = (floatx4)(0.f); accu[i][j] = (floatx4)(0.f); }

  const int kc = (lane >> 4) * 8;
  const int rb = lane & 15;

  for (int k0 = 0; k0 < K; k0 += 2 * BK) {
    gld16(a0 + k0, lA0); gld16(a0 + k0 + BK, lA1);
    gld16(g0 + k0, lG0); gld16(g0 + k0 + BK, lG1);
    gld16(u0 + k0, lU0); gld16(u0 + k0 + BK, lU1);
    __syncthreads();
#pragma unroll
    for (int h = 0; h < 2; ++h) {
      const int ho = h * BM * BK;
      short8 af[2], gf[2], uf[2];
#pragma unroll
      for (int mt = 0; mt < 2; ++mt)
        af[mt] = *(const short8*)&As[ho + (wr * 32 + mt * 16 + rb) * BK + kc];
#pragma unroll
      for (int nt = 0; nt < 2; ++nt) {
        gf[nt] = *(const short8*)&Bg[ho + (wc * 32 + nt * 16 + rb) * BK + kc];
        uf[nt] = *(const short8*)&Bu[ho + (wc * 32 + nt * 16 + rb) * BK + kc];
      }
#pragma unroll
      for (int mt = 0; mt < 2; ++mt)
#pragma unroll
        for (int nt = 0; nt < 2; ++nt) {
          accg[mt][nt] = __builtin_amdgcn_mfma_f32_16x16x32_bf16(af[mt], gf[nt], accg[mt][nt], 0, 0, 0);
          accu[mt][nt] = __builtin_amdgcn_mfma_f32_16x16x32_bf16(af[mt], uf[nt], accu[mt][nt], 0, 0, 0);
        }
    }
    __syncthreads();
  }
#pragma unroll
  for (int mt = 0; mt < 2; ++mt)
#pragma unroll
    for (int nt = 0; nt < 2; ++nt) {
      const int col = n0 + wc * 32 + nt * 16 + rb;
#pragma unroll
      for (int r = 0; r < 4; ++r) {
        const int row = m0 + wr * 32 + mt * 16 + (lane >> 4) * 4 + r;
        float s = silu_mul(accg[mt][nt][r], accu[mt][nt][r]);
        sbuf[(size_t)row * DFS + col] = f2b(s);
      }
    }
}

// Shared down (split-K x2):  shd_z[t,d] = partial, plain store.  grid (16,32,2).
__global__ __launch_bounds__(256) void mfma_shared_down(
    const ushort* __restrict__ sb, const ushort* __restrict__ wd,
    float* __restrict__ shd0, float* __restrict__ shd1) {
  __shared__ ushort As[2 * BM * BK];
  __shared__ ushort Bs[2 * BN * BK];
  const int tid = threadIdx.x;
  const int wave = tid >> 6, lane = tid & 63;
  const int wr = wave >> 1, wc = wave & 1;
  const int m0 = blockIdx.y * BM, n0 = blockIdx.x * BN;
  const int kb = blockIdx.z * (DFS / 2);
  float* dst = blockIdx.z ? shd1 : shd0;
  const int srow = lane >> 2;
  const int scol = (lane & 3) * 8;

  const ushort* a0 = sb + (size_t)(m0 + wave * 16 + srow) * DFS + kb + scol;
  const ushort* b0 = wd + (size_t)(n0 + wave * 16 + srow) * DFS + kb + scol;
  ushort* lA0 = &As[(wave * 16) * BK];  ushort* lA1 = lA0 + BM * BK;
  ushort* lB0 = &Bs[(wave * 16) * BK];  ushort* lB1 = lB0 + BN * BK;

  floatx4 acc[2][2];
#pragma unroll
  for (int i = 0; i < 2; ++i)
#pragma unroll
    for (int j = 0; j < 2; ++j) acc[i][j] = (floatx4)(0.f);

  const int kc = (lane >> 4) * 8;
  const int rb = lane & 15;

  for (int k0 = 0; k0 < DFS / 2; k0 += 2 * BK) {
    gld16(a0 + k0, lA0); gld16(a0 + k0 + BK, lA1);
    gld16(b0 + k0, lB0); gld16(b0 + k0 + BK, lB1);
    __syncthreads();
#pragma unroll
    for (int h = 0; h < 2; ++h) {
      const int ho = h * BM * BK;
      short8 af[2], bf[2];
#pragma unroll
      for (int mt = 0; mt < 2; ++mt)
        af[mt] = *(const short8*)&As[ho + (wr * 32 + mt * 16 + rb) * BK + kc];
#pragma unroll
      for (int nt = 0; nt < 2; ++nt)
        bf[nt] = *(const short8*)&Bs[ho + (wc * 32 + nt * 16 + rb) * BK + kc];
#pragma unroll
      for (int mt = 0; mt < 2; ++mt)
#pragma unroll
        for (int nt = 0; nt < 2; ++nt)
          acc[mt][nt] = __builtin_amdgcn_mfma_f32_16x16x32_bf16(af[mt], bf[nt], acc[mt][nt], 0, 0, 0);
    }
    __syncthreads();
  }
#pragma unroll
  for (int mt = 0; mt < 2; ++mt)
#pragma unroll
    for (int nt = 0; nt < 2; ++nt) {
      const int col = n0 + wc * 32 + nt * 16 + rb;
#pragma unroll
      for (int r = 0; r < 4; ++r) {
        const int row = m0 + wr * 32 + mt * 16 + (lane >> 4) * 4 + r;
        dst[(size_t)row * D_DIM + col] = acc[mt][nt][r];
      }
    }
}

// Expert gate+up (gathered):  act[base[e]+slot, f] = silu(g*gs)*(u*us), bf16.
// grid (8,32,8).
__global__ __launch_bounds__(256) void mfma_expert_gateup(
    const ushort* __restrict__ xb, const ushort* __restrict__ gq,
    const ushort* __restrict__ uq, const float* __restrict__ gate_s,
    const float* __restrict__ up_s, const int* __restrict__ cnt,
    const int* __restrict__ tok_list, ushort* __restrict__ act) {
  const int e = blockIdx.z;
  const int ce = cnt[e];
  const int m0 = blockIdx.y * BM;
  if (m0 >= ce) return;
  const int ebase = cnt[8 + e];
  const int n0 = blockIdx.x * BN;
  __shared__ ushort As[2 * BM * BK];
  __shared__ ushort Bg[2 * BN * BK];
  __shared__ ushort Bu[2 * BN * BK];
  const int tid = threadIdx.x;
  const int wave = tid >> 6, lane = tid & 63;
  const int wr = wave >> 1, wc = wave & 1;
  const int srow = lane >> 2;
  const int scol = (lane & 3) * 8;
  const int K = D_DIM;

  const int r0 = m0 + wave * 16 + srow;
  const int tk0 = (r0 < ce) ? tok_list[e * T_TOK + r0] : 0;
  const ushort* a0 = xb + (size_t)tk0 * K + scol;
  const ushort* g0 = gq + (size_t)e * DFE * D_DIM + (size_t)(n0 + wave * 16 + srow) * K + scol;
  const ushort* u0 = uq + (size_t)e * DFE * D_DIM + (size_t)(n0 + wave * 16 + srow) * K + scol;
  ushort* lA0 = &As[(wave * 16) * BK];  ushort* lA1 = lA0 + BM * BK;
  ushort* lG0 = &Bg[(wave * 16) * BK];  ushort* lG1 = lG0 + BN * BK;
  ushort* lU0 = &Bu[(wave * 16) * BK];  ushort* lU1 = lU0 + BN * BK;

  floatx4 accg[2][2], accu[2][2];
#pragma unroll
  for (int i = 0; i < 2; ++i)
#pragma unroll
    for (int j = 0; j < 2; ++j) { accg[i][j] = (floatx4)(0.f); accu[i][j] = (floatx4)(0.f); }

  const int kc = (lane >> 4) * 8;
  const int rb = lane & 15;

  for (int k0 = 0; k0 < K; k0 += 2 * BK) {
    gld16(a0 + k0, lA0); gld16(a0 + k0 + BK, lA1);
    gld16(g0 + k0, lG0); gld16(g0 + k0 + BK, lG1);
    gld16(u0 + k0, lU0); gld16(u0 + k0 + BK, lU1);
    __syncthreads();
#pragma unroll
    for (int h = 0; h < 2; ++h) {
      const int ho = h * BM * BK;
      short8 af[2], gf[2], uf[2];
#pragma unroll
      for (int mt = 0; mt < 2; ++mt)
        af[mt] = *(const short8*)&As[ho + (wr * 32 + mt * 16 + rb) * BK + kc];
#pragma unroll
      for (int nt = 0; nt < 2; ++nt) {
        gf[nt] = *(const short8*)&Bg[ho + (wc * 32 + nt * 16 + rb) * BK + kc];
        uf[nt] = *(const short8*)&Bu[ho + (wc * 32 + nt * 16 + rb) * BK + kc];
      }
#pragma unroll
      for (int mt = 0; mt < 2; ++mt)
#pragma unroll
        for (int nt = 0; nt < 2; ++nt) {
          accg[mt][nt] = __builtin_amdgcn_mfma_f32_16x16x32_bf16(af[mt], gf[nt], accg[mt][nt], 0, 0, 0);
          accu[mt][nt] = __builtin_amdgcn_mfma_f32_16x16x32_bf16(af[mt], uf[nt], accu[mt][nt], 0, 0, 0);
        }
    }
    __syncthreads();
  }
#pragma unroll
  for (int mt = 0; mt < 2; ++mt)
#pragma unroll
    for (int nt = 0; nt < 2; ++nt) {
      const int col = n0 + wc * 32 + nt * 16 + rb;
      const float gsc = gate_s[e * DFE + col];
      const float usc = up_s[e * DFE + col];
#pragma unroll
      for (int r = 0; r < 4; ++r) {
        const int slot = m0 + wr * 32 + mt * 16 + (lane >> 4) * 4 + r;
        if (slot < ce) {   // compacted layout: must not stomp next expert
          float s = silu_mul(accg[mt][nt][r] * gsc, accu[mt][nt][r] * usc);
          act[(size_t)(ebase + slot) * DFE + col] = f2b(s);
        }
      }
    }
}

// Expert down:  pbuf[base[e]+slot, d] = partial * down_s[d], plain store.
// grid (16,32,8).
__global__ __launch_bounds__(256) void mfma_expert_down(
    const ushort* __restrict__ act, const ushort* __restrict__ dq,
    const float* __restrict__ down_s, const int* __restrict__ cnt,
    float* __restrict__ pbuf) {
  const int e = blockIdx.z;
  const int ce = cnt[e];
  const int m0 = blockIdx.y * BM;
  if (m0 >= ce) return;
  const int ebase = cnt[8 + e];
  const int n0 = blockIdx.x * BN;
  __shared__ ushort As[2 * BM * BK];
  __shared__ ushort Bs[2 * BN * BK];
  const int tid = threadIdx.x;
  const int wave = tid >> 6, lane = tid & 63;
  const int wr = wave >> 1, wc = wave & 1;
  const int srow = lane >> 2;
  const int scol = (lane & 3) * 8;

  // A rows: compacted act rows (reads past ce feed only discarded rows;
  // buffer has slack after).
  const ushort* a0 = act + (size_t)(ebase + m0 + wave * 16 + srow) * DFE + scol;
  const ushort* b0 = dq + (size_t)e * D_DIM * DFE + (size_t)(n0 + wave * 16 + srow) * DFE + scol;
  ushort* lA0 = &As[(wave * 16) * BK];  ushort* lA1 = lA0 + BM * BK;
  ushort* lB0 = &Bs[(wave * 16) * BK];  ushort* lB1 = lB0 + BN * BK;

  floatx4 acc[2][2];
#pragma unroll
  for (int i = 0; i < 2; ++i)
#pragma unroll
    for (int j = 0; j < 2; ++j) acc[i][j] = (floatx4)(0.f);

  const int kc = (lane >> 4) * 8;
  const int rb = lane & 15;

  for (int k0 = 0; k0 < DFE; k0 += 2 * BK) {
    gld16(a0 + k0, lA0); gld16(a0 + k0 + BK, lA1);
    gld16(b0 + k0, lB0); gld16(b0 + k0 + BK, lB1);
    __syncthreads();
#pragma unroll
    for (int h = 0; h < 2; ++h) {
      const int ho = h * BM * BK;
      short8 af[2], bf[2];
#pragma unroll
      for (int mt = 0; mt < 2; ++mt)
        af[mt] = *(const short8*)&As[ho + (wr * 32 + mt * 16 + rb) * BK + kc];
#pragma unroll
      for (int nt = 0; nt < 2; ++nt)
        bf[nt] = *(const short8*)&Bs[ho + (wc * 32 + nt * 16 + rb) * BK + kc];
#pragma unroll
      for (int mt = 0; mt < 2; ++mt)
#pragma unroll
        for (int nt = 0; nt < 2; ++nt)
          acc[mt][nt] = __builtin_amdgcn_mfma_f32_16x16x32_bf16(af[mt], bf[nt], acc[mt][nt], 0, 0, 0);
    }
    __syncthreads();
  }
#pragma unroll
  for (int mt = 0; mt < 2; ++mt)
#pragma unroll
    for (int nt = 0; nt < 2; ++nt) {
      const int col = n0 + wc * 32 + nt * 16 + rb;
      const float dsc = down_s[e * D_DIM + col];
#pragma unroll
      for (int r = 0; r < 4; ++r) {
        const int slot = m0 + wr * 32 + mt * 16 + (lane >> 4) * 4 + r;
        if (slot < ce)
          pbuf[(size_t)(ebase + slot) * D_DIM + col] = acc[mt][nt][r] * dsc;
      }
    }
}

// ---------------------------------------------------------------------------
// combine: out[t] = (1-csum)*(shd0+shd1) + c0*pbuf[a0] + c1*pbuf[a1]
// ---------------------------------------------------------------------------
__global__ __launch_bounds__(256) void combine_kernel(
    const float* __restrict__ shd0, const float* __restrict__ shd1,
    const float* __restrict__ pbuf, const float* __restrict__ csum,
    const float2* __restrict__ cpair, const uint2* __restrict__ ass,
    float* __restrict__ out) {
  const int t = blockIdx.x;
  const int c4 = threadIdx.x * 4;
  const float cs = 1.f - csum[t];
  const float2 cp = cpair[t];
  const uint2 a = ass[t];
  const size_t idx = (size_t)t * D_DIM + c4;
  float4 s0 = *(const float4*)(shd0 + idx);
  float4 s1 = *(const float4*)(shd1 + idx);
  float4 e0 = *(const float4*)(pbuf + (size_t)a.x * D_DIM + c4);
  float4 e1 = *(const float4*)(pbuf + (size_t)a.y * D_DIM + c4);
  float4 o;
  o.x = cs * (s0.x + s1.x) + cp.x * e0.x + cp.y * e1.x;
  o.y = cs * (s0.y + s1.y) + cp.x * e0.y + cp.y * e1.y;
  o.z = cs * (s0.z + s1.z) + cp.x * e0.z + cp.y * e1.z;
  o.w = cs * (s0.w + s1.w) + cp.x * e0.w + cp.y * e1.w;
  *(float4*)(out + idx) = o;
}

// ---------------------------------------------------------------------------
extern "C" void kernel_launch(void* const* d_in, const int* in_sizes, int n_in,
                              void* d_out, int out_size, void* d_ws, size_t ws_size,
                              hipStream_t stream) {
  const float* x         = (const float*)d_in[0];
  const float* rw        = (const float*)d_in[1];
  const float* sh_gate_w = (const float*)d_in[2];
  const float* sh_up_w   = (const float*)d_in[3];
  const float* sh_down_w = (const float*)d_in[4];
  const float* gate_s    = (const float*)d_in[5];
  const float* up_s      = (const float*)d_in[6];
  const float* down_s    = (const float*)d_in[7];
  const float* alpha     = (const float*)d_in[8];
  const int*   gate_q    = (const int*)d_in[9];
  const int*   up_q      = (const int*)d_in[10];
  const int*   down_q    = (const int*)d_in[11];

  char* ws = (char*)d_ws;
  const size_t MB = 1u << 20;
  // Workspace map (61 MB total):
  int*    cnt      = (int*)ws;                 // 64 B: cnt[0..7], base[8..15]
  int*    tok_list = (int*)(ws + 1024);        // 64 KB
  float*  csum     = (float*)(ws + 66560);     // 8 KB
  int*    choice   = (int*)(ws + 74752);       // 8 KB
  float2* cpair    = (float2*)(ws + 82944);    // 16 KB
  uint2*  ass      = (uint2*)(ws + 99328);     // 16 KB
  ushort* xb      = (ushort*)(ws + 1 * MB);    // 4 MB  [2048,1024]
  ushort* sgb     = (ushort*)(ws + 5 * MB);    // 4 MB  [2048,1024]
  ushort* sub     = (ushort*)(ws + 9 * MB);    // 4 MB  [2048,1024]
  float*  shd0    = (float*)(ws + 5 * MB);     // 8 MB fp32, overlays sgb+sub
                                               // (dead after shared_gateup)
  ushort* sbuf    = (ushort*)(ws + 13 * MB);   // 8 MB  [2048,2048]
  ushort* sdb     = (ushort*)(ws + 21 * MB);   // 4 MB  [1024,2048]
  ushort* gqb     = (ushort*)(ws + 25 * MB);   // 8 MB  [8,512,1024]
  ushort* uqb     = (ushort*)(ws + 33 * MB);   // 8 MB  [8,512,1024]
  float*  pbuf    = (float*)(ws + 25 * MB);    // 16 MB [4096,1024] fp32,
                                               // overlays gqb+uqb (dead after expert_gateup)
  ushort* dqb     = (ushort*)(ws + 41 * MB);   // 8 MB  [8,1024,512]
  ushort* act     = (ushort*)(ws + 49 * MB);   // 4 MB  [4096,512] bf16 (compacted)
  float*  shd1    = (float*)(ws + 53 * MB);    // 8 MB  [2048,1024] fp32

  float* out = (float*)d_out;

  mega_prep<<<9728, 256, 0, stream>>>(
      x, rw, alpha, sh_gate_w, sh_up_w, sh_down_w, gate_q, up_q, down_q,
      choice, cpair, csum, xb, sgb, sub, sdb, gqb, uqb, dqb);
  build_lists<<<1, 1024, 0, stream>>>(choice, cnt, tok_list, ass);

  mfma_shared_gateup<<<dim3(DFS / BN, T_TOK / BM), 256, 0, stream>>>(xb, sgb, sub, sbuf);
  mfma_expert_gateup<<<dim3(DFE / BN, T_TOK / BM, E_NUM), 256, 0, stream>>>(
      xb, gqb, uqb, gate_s, up_s, cnt, tok_list, act);
  mfma_shared_down<<<dim3(D_DIM / BN, T_TOK / BM, 2), 256, 0, stream>>>(sbuf, sdb, shd0, shd1);
  mfma_expert_down<<<dim3(D_DIM / BN, T_TOK / BM, E_NUM), 256, 0, stream>>>(
      act, dqb, down_s, cnt, pbuf);
  combine_kernel<<<T_TOK, 256, 0, stream>>>(shd0, shd1, pbuf, csum, cpair, ass, out);
}

// Round 13
// 230.450 us; speedup vs baseline: 1.9376x; 1.0316x over previous
//
#include <hip/hip_runtime.h>
#include <math.h>

// Problem constants (from setup_inputs)
#define T_TOK 2048   // B*S
#define D_DIM 1024   // hidden
#define E_NUM 8      // experts
#define DFS   2048   // shared ffn
#define DFE   512    // expert ffn

// GEMM tile: 64x64, 4 waves, each wave 32x32 (acc[2][2]).
// K-loop steps by 128 = four BK=32 stages per barrier pair.
#define BM 64
#define BN 64
#define BK 32
#define KSTEP 128
#define NSUB 4

typedef short short8 __attribute__((ext_vector_type(8)));
typedef float floatx4 __attribute__((ext_vector_type(4)));
typedef unsigned short ushort;

// float -> bf16 (RNE)
__device__ __forceinline__ ushort f2b(float f) {
  union { float f; unsigned u; } v; v.f = f;
  unsigned r = (v.u + 0x7fffu + ((v.u >> 16) & 1u)) >> 16;
  return (ushort)r;
}

// async global->LDS, 16B per lane. lds ptr must be wave-uniform.
__device__ __forceinline__ void gld16(const ushort* g, ushort* l) {
  __builtin_amdgcn_global_load_lds(
      (const __attribute__((address_space(1))) void*)g,
      (__attribute__((address_space(3))) void*)l,
      16, 0, 0);
}

__device__ __forceinline__ float silu_mul(float g, float u) {
  return (g / (1.f + __expf(-g))) * u;
}

// ---------------------------------------------------------------------------
// mega_prep: router (+x->bf16), fp32 weight cvt, int32 quant cvt.
// grid.x = 512 + 3072 + 6144 = 9728, block 256.
// ---------------------------------------------------------------------------
__global__ __launch_bounds__(256) void mega_prep(
    const float* __restrict__ x, const float* __restrict__ rw,
    const float* __restrict__ alpha,
    const float* __restrict__ sg, const float* __restrict__ su,
    const float* __restrict__ sd,
    const int* __restrict__ gq, const int* __restrict__ uq,
    const int* __restrict__ dq,
    int* __restrict__ choice, float2* __restrict__ cpair,
    float* __restrict__ csum, ushort* __restrict__ xb,
    ushort* __restrict__ sgb, ushort* __restrict__ subb,
    ushort* __restrict__ sdb,
    ushort* __restrict__ gqb, ushort* __restrict__ uqb,
    ushort* __restrict__ dqb) {
  const int b = blockIdx.x;
  const int tid = threadIdx.x;
  if (b < 512) {
    __shared__ float xs[4 * D_DIM];
    const size_t base = (size_t)b * 4 * D_DIM;
#pragma unroll
    for (int j = 0; j < 4; ++j) {
      const int idx = j * 1024 + tid * 4;
      float4 v = *(const float4*)(x + base + idx);
      *(float4*)&xs[idx] = v;
      union { ushort u[4]; uint2 p; } o;
      o.u[0] = f2b(v.x); o.u[1] = f2b(v.y); o.u[2] = f2b(v.z); o.u[3] = f2b(v.w);
      *(uint2*)(xb + base + idx) = o.p;
    }
    __syncthreads();
    const int w = tid >> 6, l = tid & 63;
    const int t = b * 4 + w;
    const int e = l >> 3, sub = l & 7;
    const float* wr = rw + e * D_DIM;
    float acc = 0.f;
#pragma unroll
    for (int k = 0; k < 32; ++k) {
      const int d = k * 32 + sub * 4;
      float4 xv = *(const float4*)&xs[w * D_DIM + d];
      float4 wv = *(const float4*)(wr + d);
      acc += xv.x * wv.x + xv.y * wv.y + xv.z * wv.z + xv.w * wv.w;
    }
    acc += __shfl_xor(acc, 1);
    acc += __shfl_xor(acc, 2);
    acc += __shfl_xor(acc, 4);
    float lg[8];
#pragma unroll
    for (int i = 0; i < 8; ++i) lg[i] = __shfl(acc, i * 8);
    if (l == 0) {
      int i0 = 0; float v0 = lg[0];
#pragma unroll
      for (int i = 1; i < E_NUM; ++i) if (lg[i] > v0) { v0 = lg[i]; i0 = i; }
      int i1 = -1; float v1 = -1e30f;
#pragma unroll
      for (int i = 0; i < E_NUM; ++i) {
        if (i == i0) continue;
        if (lg[i] > v1) { v1 = lg[i]; i1 = i; }
      }
      float w0 = 1.f / (1.f + __expf(v1 - v0));
      float w1 = 1.f - w0;
      float c0 = w0 * alpha[i0];
      float c1 = w1 * alpha[i1];
      csum[t] = c0 + c1;
      choice[t] = i0 | (i1 << 4);
      cpair[t] = make_float2(c0, c1);
    }
  } else if (b < 512 + 3072) {
    const int bb = b - 512;
    const int which = bb >> 10;
    const float* src; ushort* dst;
    if (which == 0) { src = sg; dst = sgb; }
    else if (which == 1) { src = su; dst = subb; }
    else { src = sd; dst = sdb; }
    const size_t i = (size_t)(bb & 1023) * 256 + tid;
    const float4* sp = (const float4*)src;
    float4 a = sp[2 * i], c = sp[2 * i + 1];
    union { ushort u[8]; uint4 v; } o;
    o.u[0] = f2b(a.x); o.u[1] = f2b(a.y); o.u[2] = f2b(a.z); o.u[3] = f2b(a.w);
    o.u[4] = f2b(c.x); o.u[5] = f2b(c.y); o.u[6] = f2b(c.z); o.u[7] = f2b(c.w);
    ((uint4*)dst)[i] = o.v;
  } else {
    const int bb = b - 3584;
    const int which = bb >> 11;
    const int* src; ushort* dst;
    if (which == 0) { src = gq; dst = gqb; }
    else if (which == 1) { src = uq; dst = uqb; }
    else { src = dq; dst = dqb; }
    const size_t i = (size_t)(bb & 2047) * 256 + tid;
    const int4* sp = (const int4*)src;
    int4 a = sp[2 * i], c = sp[2 * i + 1];
    union { ushort u[8]; uint4 v; } o;
    o.u[0] = f2b((float)a.x); o.u[1] = f2b((float)a.y);
    o.u[2] = f2b((float)a.z); o.u[3] = f2b((float)a.w);
    o.u[4] = f2b((float)c.x); o.u[5] = f2b((float)c.y);
    o.u[6] = f2b((float)c.z); o.u[7] = f2b((float)c.w);
    ((uint4*)dst)[i] = o.v;
  }
}

// ---------------------------------------------------------------------------
// build_lists: single block; counts cnt[e], bases cnt[8+e], inverse map ass.
// ---------------------------------------------------------------------------
__global__ __launch_bounds__(1024) void build_lists(
    const int* __restrict__ choice, int* __restrict__ cnt,
    int* __restrict__ tok_list, uint2* __restrict__ ass) {
  __shared__ int lcnt[E_NUM];
  __shared__ int lbase[E_NUM];
  const int tid = threadIdx.x;
  if (tid < E_NUM) lcnt[tid] = 0;
  __syncthreads();
  uint2 tmp[T_TOK / 1024];
#pragma unroll
  for (int r = 0; r < T_TOK / 1024; ++r) {
    const int t = r * 1024 + tid;
    const int ch = choice[t];
    const int i0 = ch & 15, i1 = ch >> 4;
    const int p0 = atomicAdd(&lcnt[i0], 1);
    tok_list[i0 * T_TOK + p0] = t;
    const int p1 = atomicAdd(&lcnt[i1], 1);
    tok_list[i1 * T_TOK + p1] = t;
    tmp[r] = make_uint2((unsigned)((i0 << 16) | p0), (unsigned)((i1 << 16) | p1));
  }
  __syncthreads();
  if (tid < E_NUM) {
    int b = 0;
    for (int i = 0; i < tid; ++i) b += lcnt[i];
    lbase[tid] = b;
    cnt[tid] = lcnt[tid];
    cnt[8 + tid] = b;
  }
  __syncthreads();
#pragma unroll
  for (int r = 0; r < T_TOK / 1024; ++r) {
    const int t = r * 1024 + tid;
    const uint2 v = tmp[r];
    ass[t] = make_uint2(lbase[v.x >> 16] + (v.x & 0xffffu),
                        lbase[v.y >> 16] + (v.y & 0xffffu));
  }
}

// ---------------------------------------------------------------------------
// GEMMs: 64x64 tile, K-step 128 (four BK=32 sub-stages per barrier pair).
// Wave w stages rows [w*16, w*16+16) of each sub-tile (1 gld16 each).
// ---------------------------------------------------------------------------

// Shared gate+up:  sbuf = silu(x@Wg^T) * (x@Wu^T), bf16.  grid (32, 32).
__global__ __launch_bounds__(256) void mfma_shared_gateup(
    const ushort* __restrict__ xb, const ushort* __restrict__ wg,
    const ushort* __restrict__ wu, ushort* __restrict__ sbuf) {
  __shared__ ushort As[NSUB * BM * BK];
  __shared__ ushort Bg[NSUB * BN * BK];
  __shared__ ushort Bu[NSUB * BN * BK];
  const int tid = threadIdx.x;
  const int wave = tid >> 6, lane = tid & 63;
  const int wr = wave >> 1, wc = wave & 1;
  const int m0 = blockIdx.y * BM, n0 = blockIdx.x * BN;
  const int srow = lane >> 2;
  const int scol = (lane & 3) * 8;
  const int K = D_DIM;

  const ushort* a0 = xb + (size_t)(m0 + wave * 16 + srow) * K + scol;
  const ushort* g0 = wg + (size_t)(n0 + wave * 16 + srow) * K + scol;
  const ushort* u0 = wu + (size_t)(n0 + wave * 16 + srow) * K + scol;
  ushort* lA0 = &As[(wave * 16) * BK];
  ushort* lG0 = &Bg[(wave * 16) * BK];
  ushort* lU0 = &Bu[(wave * 16) * BK];

  floatx4 accg[2][2], accu[2][2];
#pragma unroll
  for (int i = 0; i < 2; ++i)
#pragma unroll
    for (int j = 0; j < 2; ++j) { accg[i][j] = (floatx4)(0.f); accu[i][j] = (floatx4)(0.f); }

  const int kc = (lane >> 4) * 8;
  const int rb = lane & 15;

  for (int k0 = 0; k0 < K; k0 += KSTEP) {
#pragma unroll
    for (int h = 0; h < NSUB; ++h) {
      gld16(a0 + k0 + h * BK, lA0 + h * BM * BK);
      gld16(g0 + k0 + h * BK, lG0 + h * BN * BK);
      gld16(u0 + k0 + h * BK, lU0 + h * BN * BK);
    }
    __syncthreads();
#pragma unroll
    for (int h = 0; h < NSUB; ++h) {
      const int ho = h * BM * BK;
      short8 af[2], gf[2], uf[2];
#pragma unroll
      for (int mt = 0; mt < 2; ++mt)
        af[mt] = *(const short8*)&As[ho + (wr * 32 + mt * 16 + rb) * BK + kc];
#pragma unroll
      for (int nt = 0; nt < 2; ++nt) {
        gf[nt] = *(const short8*)&Bg[ho + (wc * 32 + nt * 16 + rb) * BK + kc];
        uf[nt] = *(const short8*)&Bu[ho + (wc * 32 + nt * 16 + rb) * BK + kc];
      }
#pragma unroll
      for (int mt = 0; mt < 2; ++mt)
#pragma unroll
        for (int nt = 0; nt < 2; ++nt) {
          accg[mt][nt] = __builtin_amdgcn_mfma_f32_16x16x32_bf16(af[mt], gf[nt], accg[mt][nt], 0, 0, 0);
          accu[mt][nt] = __builtin_amdgcn_mfma_f32_16x16x32_bf16(af[mt], uf[nt], accu[mt][nt], 0, 0, 0);
        }
    }
    __syncthreads();
  }
#pragma unroll
  for (int mt = 0; mt < 2; ++mt)
#pragma unroll
    for (int nt = 0; nt < 2; ++nt) {
      const int col = n0 + wc * 32 + nt * 16 + rb;
#pragma unroll
      for (int r = 0; r < 4; ++r) {
        const int row = m0 + wr * 32 + mt * 16 + (lane >> 4) * 4 + r;
        float s = silu_mul(accg[mt][nt][r], accu[mt][nt][r]);
        sbuf[(size_t)row * DFS + col] = f2b(s);
      }
    }
}

// Shared down (split-K x2):  shd_z[t,d] = partial, plain store.  grid (16,32,2).
__global__ __launch_bounds__(256) void mfma_shared_down(
    const ushort* __restrict__ sb, const ushort* __restrict__ wd,
    float* __restrict__ shd0, float* __restrict__ shd1) {
  __shared__ ushort As[NSUB * BM * BK];
  __shared__ ushort Bs[NSUB * BN * BK];
  const int tid = threadIdx.x;
  const int wave = tid >> 6, lane = tid & 63;
  const int wr = wave >> 1, wc = wave & 1;
  const int m0 = blockIdx.y * BM, n0 = blockIdx.x * BN;
  const int kb = blockIdx.z * (DFS / 2);
  float* dst = blockIdx.z ? shd1 : shd0;
  const int srow = lane >> 2;
  const int scol = (lane & 3) * 8;

  const ushort* a0 = sb + (size_t)(m0 + wave * 16 + srow) * DFS + kb + scol;
  const ushort* b0 = wd + (size_t)(n0 + wave * 16 + srow) * DFS + kb + scol;
  ushort* lA0 = &As[(wave * 16) * BK];
  ushort* lB0 = &Bs[(wave * 16) * BK];

  floatx4 acc[2][2];
#pragma unroll
  for (int i = 0; i < 2; ++i)
#pragma unroll
    for (int j = 0; j < 2; ++j) acc[i][j] = (floatx4)(0.f);

  const int kc = (lane >> 4) * 8;
  const int rb = lane & 15;

  for (int k0 = 0; k0 < DFS / 2; k0 += KSTEP) {
#pragma unroll
    for (int h = 0; h < NSUB; ++h) {
      gld16(a0 + k0 + h * BK, lA0 + h * BM * BK);
      gld16(b0 + k0 + h * BK, lB0 + h * BN * BK);
    }
    __syncthreads();
#pragma unroll
    for (int h = 0; h < NSUB; ++h) {
      const int ho = h * BM * BK;
      short8 af[2], bf[2];
#pragma unroll
      for (int mt = 0; mt < 2; ++mt)
        af[mt] = *(const short8*)&As[ho + (wr * 32 + mt * 16 + rb) * BK + kc];
#pragma unroll
      for (int nt = 0; nt < 2; ++nt)
        bf[nt] = *(const short8*)&Bs[ho + (wc * 32 + nt * 16 + rb) * BK + kc];
#pragma unroll
      for (int mt = 0; mt < 2; ++mt)
#pragma unroll
        for (int nt = 0; nt < 2; ++nt)
          acc[mt][nt] = __builtin_amdgcn_mfma_f32_16x16x32_bf16(af[mt], bf[nt], acc[mt][nt], 0, 0, 0);
    }
    __syncthreads();
  }
#pragma unroll
  for (int mt = 0; mt < 2; ++mt)
#pragma unroll
    for (int nt = 0; nt < 2; ++nt) {
      const int col = n0 + wc * 32 + nt * 16 + rb;
#pragma unroll
      for (int r = 0; r < 4; ++r) {
        const int row = m0 + wr * 32 + mt * 16 + (lane >> 4) * 4 + r;
        dst[(size_t)row * D_DIM + col] = acc[mt][nt][r];
      }
    }
}

// Expert gate+up (gathered):  act[base[e]+slot, f] = silu(g*gs)*(u*us), bf16.
// grid (8,32,8).
__global__ __launch_bounds__(256) void mfma_expert_gateup(
    const ushort* __restrict__ xb, const ushort* __restrict__ gq,
    const ushort* __restrict__ uq, const float* __restrict__ gate_s,
    const float* __restrict__ up_s, const int* __restrict__ cnt,
    const int* __restrict__ tok_list, ushort* __restrict__ act) {
  const int e = blockIdx.z;
  const int ce = cnt[e];
  const int m0 = blockIdx.y * BM;
  if (m0 >= ce) return;
  const int ebase = cnt[8 + e];
  const int n0 = blockIdx.x * BN;
  __shared__ ushort As[NSUB * BM * BK];
  __shared__ ushort Bg[NSUB * BN * BK];
  __shared__ ushort Bu[NSUB * BN * BK];
  const int tid = threadIdx.x;
  const int wave = tid >> 6, lane = tid & 63;
  const int wr = wave >> 1, wc = wave & 1;
  const int srow = lane >> 2;
  const int scol = (lane & 3) * 8;
  const int K = D_DIM;

  const int r0 = m0 + wave * 16 + srow;
  const int tk0 = (r0 < ce) ? tok_list[e * T_TOK + r0] : 0;
  const ushort* a0 = xb + (size_t)tk0 * K + scol;
  const ushort* g0 = gq + (size_t)e * DFE * D_DIM + (size_t)(n0 + wave * 16 + srow) * K + scol;
  const ushort* u0 = uq + (size_t)e * DFE * D_DIM + (size_t)(n0 + wave * 16 + srow) * K + scol;
  ushort* lA0 = &As[(wave * 16) * BK];
  ushort* lG0 = &Bg[(wave * 16) * BK];
  ushort* lU0 = &Bu[(wave * 16) * BK];

  floatx4 accg[2][2], accu[2][2];
#pragma unroll
  for (int i = 0; i < 2; ++i)
#pragma unroll
    for (int j = 0; j < 2; ++j) { accg[i][j] = (floatx4)(0.f); accu[i][j] = (floatx4)(0.f); }

  const int kc = (lane >> 4) * 8;
  const int rb = lane & 15;

  for (int k0 = 0; k0 < K; k0 += KSTEP) {
#pragma unroll
    for (int h = 0; h < NSUB; ++h) {
      gld16(a0 + k0 + h * BK, lA0 + h * BM * BK);
      gld16(g0 + k0 + h * BK, lG0 + h * BN * BK);
      gld16(u0 + k0 + h * BK, lU0 + h * BN * BK);
    }
    __syncthreads();
#pragma unroll
    for (int h = 0; h < NSUB; ++h) {
      const int ho = h * BM * BK;
      short8 af[2], gf[2], uf[2];
#pragma unroll
      for (int mt = 0; mt < 2; ++mt)
        af[mt] = *(const short8*)&As[ho + (wr * 32 + mt * 16 + rb) * BK + kc];
#pragma unroll
      for (int nt = 0; nt < 2; ++nt) {
        gf[nt] = *(const short8*)&Bg[ho + (wc * 32 + nt * 16 + rb) * BK + kc];
        uf[nt] = *(const short8*)&Bu[ho + (wc * 32 + nt * 16 + rb) * BK + kc];
      }
#pragma unroll
      for (int mt = 0; mt < 2; ++mt)
#pragma unroll
        for (int nt = 0; nt < 2; ++nt) {
          accg[mt][nt] = __builtin_amdgcn_mfma_f32_16x16x32_bf16(af[mt], gf[nt], accg[mt][nt], 0, 0, 0);
          accu[mt][nt] = __builtin_amdgcn_mfma_f32_16x16x32_bf16(af[mt], uf[nt], accu[mt][nt], 0, 0, 0);
        }
    }
    __syncthreads();
  }
#pragma unroll
  for (int mt = 0; mt < 2; ++mt)
#pragma unroll
    for (int nt = 0; nt < 2; ++nt) {
      const int col = n0 + wc * 32 + nt * 16 + rb;
      const float gsc = gate_s[e * DFE + col];
      const float usc = up_s[e * DFE + col];
#pragma unroll
      for (int r = 0; r < 4; ++r) {
        const int slot = m0 + wr * 32 + mt * 16 + (lane >> 4) * 4 + r;
        if (slot < ce) {   // compacted layout: must not stomp next expert
          float s = silu_mul(accg[mt][nt][r] * gsc, accu[mt][nt][r] * usc);
          act[(size_t)(ebase + slot) * DFE + col] = f2b(s);
        }
      }
    }
}

// Expert down:  pbuf[base[e]+slot, d] = partial * down_s[d], plain store.
// grid (16,32,8).
__global__ __launch_bounds__(256) void mfma_expert_down(
    const ushort* __restrict__ act, const ushort* __restrict__ dq,
    const float* __restrict__ down_s, const int* __restrict__ cnt,
    float* __restrict__ pbuf) {
  const int e = blockIdx.z;
  const int ce = cnt[e];
  const int m0 = blockIdx.y * BM;
  if (m0 >= ce) return;
  const int ebase = cnt[8 + e];
  const int n0 = blockIdx.x * BN;
  __shared__ ushort As[NSUB * BM * BK];
  __shared__ ushort Bs[NSUB * BN * BK];
  const int tid = threadIdx.x;
  const int wave = tid >> 6, lane = tid & 63;
  const int wr = wave >> 1, wc = wave & 1;
  const int srow = lane >> 2;
  const int scol = (lane & 3) * 8;

  // A rows: compacted act rows (reads past ce feed only discarded rows;
  // buffer has slack after).
  const ushort* a0 = act + (size_t)(ebase + m0 + wave * 16 + srow) * DFE + scol;
  const ushort* b0 = dq + (size_t)e * D_DIM * DFE + (size_t)(n0 + wave * 16 + srow) * DFE + scol;
  ushort* lA0 = &As[(wave * 16) * BK];
  ushort* lB0 = &Bs[(wave * 16) * BK];

  floatx4 acc[2][2];
#pragma unroll
  for (int i = 0; i < 2; ++i)
#pragma unroll
    for (int j = 0; j < 2; ++j) acc[i][j] = (floatx4)(0.f);

  const int kc = (lane >> 4) * 8;
  const int rb = lane & 15;

  for (int k0 = 0; k0 < DFE; k0 += KSTEP) {
#pragma unroll
    for (int h = 0; h < NSUB; ++h) {
      gld16(a0 + k0 + h * BK, lA0 + h * BM * BK);
      gld16(b0 + k0 + h * BK, lB0 + h * BN * BK);
    }
    __syncthreads();
#pragma unroll
    for (int h = 0; h < NSUB; ++h) {
      const int ho = h * BM * BK;
      short8 af[2], bf[2];
#pragma unroll
      for (int mt = 0; mt < 2; ++mt)
        af[mt] = *(const short8*)&As[ho + (wr * 32 + mt * 16 + rb) * BK + kc];
#pragma unroll
      for (int nt = 0; nt < 2; ++nt)
        bf[nt] = *(const short8*)&Bs[ho + (wc * 32 + nt * 16 + rb) * BK + kc];
#pragma unroll
      for (int mt = 0; mt < 2; ++mt)
#pragma unroll
        for (int nt = 0; nt < 2; ++nt)
          acc[mt][nt] = __builtin_amdgcn_mfma_f32_16x16x32_bf16(af[mt], bf[nt], acc[mt][nt], 0, 0, 0);
    }
    __syncthreads();
  }
#pragma unroll
  for (int mt = 0; mt < 2; ++mt)
#pragma unroll
    for (int nt = 0; nt < 2; ++nt) {
      const int col = n0 + wc * 32 + nt * 16 + rb;
      const float dsc = down_s[e * D_DIM + col];
#pragma unroll
      for (int r = 0; r < 4; ++r) {
        const int slot = m0 + wr * 32 + mt * 16 + (lane >> 4) * 4 + r;
        if (slot < ce)
          pbuf[(size_t)(ebase + slot) * D_DIM + col] = acc[mt][nt][r] * dsc;
      }
    }
}

// ---------------------------------------------------------------------------
// combine: out[t] = (1-csum)*(shd0+shd1) + c0*pbuf[a0] + c1*pbuf[a1]
// ---------------------------------------------------------------------------
__global__ __launch_bounds__(256) void combine_kernel(
    const float* __restrict__ shd0, const float* __restrict__ shd1,
    const float* __restrict__ pbuf, const float* __restrict__ csum,
    const float2* __restrict__ cpair, const uint2* __restrict__ ass,
    float* __restrict__ out) {
  const int t = blockIdx.x;
  const int c4 = threadIdx.x * 4;
  const float cs = 1.f - csum[t];
  const float2 cp = cpair[t];
  const uint2 a = ass[t];
  const size_t idx = (size_t)t * D_DIM + c4;
  float4 s0 = *(const float4*)(shd0 + idx);
  float4 s1 = *(const float4*)(shd1 + idx);
  float4 e0 = *(const float4*)(pbuf + (size_t)a.x * D_DIM + c4);
  float4 e1 = *(const float4*)(pbuf + (size_t)a.y * D_DIM + c4);
  float4 o;
  o.x = cs * (s0.x + s1.x) + cp.x * e0.x + cp.y * e1.x;
  o.y = cs * (s0.y + s1.y) + cp.x * e0.y + cp.y * e1.y;
  o.z = cs * (s0.z + s1.z) + cp.x * e0.z + cp.y * e1.z;
  o.w = cs * (s0.w + s1.w) + cp.x * e0.w + cp.y * e1.w;
  *(float4*)(out + idx) = o;
}

// ---------------------------------------------------------------------------
extern "C" void kernel_launch(void* const* d_in, const int* in_sizes, int n_in,
                              void* d_out, int out_size, void* d_ws, size_t ws_size,
                              hipStream_t stream) {
  const float* x         = (const float*)d_in[0];
  const float* rw        = (const float*)d_in[1];
  const float* sh_gate_w = (const float*)d_in[2];
  const float* sh_up_w   = (const float*)d_in[3];
  const float* sh_down_w = (const float*)d_in[4];
  const float* gate_s    = (const float*)d_in[5];
  const float* up_s      = (const float*)d_in[6];
  const float* down_s    = (const float*)d_in[7];
  const float* alpha     = (const float*)d_in[8];
  const int*   gate_q    = (const int*)d_in[9];
  const int*   up_q      = (const int*)d_in[10];
  const int*   down_q    = (const int*)d_in[11];

  char* ws = (char*)d_ws;
  const size_t MB = 1u << 20;
  // Workspace map (61 MB total):
  int*    cnt      = (int*)ws;                 // 64 B: cnt[0..7], base[8..15]
  int*    tok_list = (int*)(ws + 1024);        // 64 KB
  float*  csum     = (float*)(ws + 66560);     // 8 KB
  int*    choice   = (int*)(ws + 74752);       // 8 KB
  float2* cpair    = (float2*)(ws + 82944);    // 16 KB
  uint2*  ass      = (uint2*)(ws + 99328);     // 16 KB
  ushort* xb      = (ushort*)(ws + 1 * MB);    // 4 MB  [2048,1024]
  ushort* sgb     = (ushort*)(ws + 5 * MB);    // 4 MB  [2048,1024]
  ushort* sub     = (ushort*)(ws + 9 * MB);    // 4 MB  [2048,1024]
  float*  shd0    = (float*)(ws + 5 * MB);     // 8 MB fp32, overlays sgb+sub
                                               // (dead after shared_gateup)
  ushort* sbuf    = (ushort*)(ws + 13 * MB);   // 8 MB  [2048,2048]
  ushort* sdb     = (ushort*)(ws + 21 * MB);   // 4 MB  [1024,2048]
  ushort* gqb     = (ushort*)(ws + 25 * MB);   // 8 MB  [8,512,1024]
  ushort* uqb     = (ushort*)(ws + 33 * MB);   // 8 MB  [8,512,1024]
  float*  pbuf    = (float*)(ws + 25 * MB);    // 16 MB [4096,1024] fp32,
                                               // overlays gqb+uqb (dead after expert_gateup)
  ushort* dqb     = (ushort*)(ws + 41 * MB);   // 8 MB  [8,1024,512]
  ushort* act     = (ushort*)(ws + 49 * MB);   // 4 MB  [4096,512] bf16 (compacted)
  float*  shd1    = (float*)(ws + 53 * MB);    // 8 MB  [2048,1024] fp32

  float* out = (float*)d_out;

  mega_prep<<<9728, 256, 0, stream>>>(
      x, rw, alpha, sh_gate_w, sh_up_w, sh_down_w, gate_q, up_q, down_q,
      choice, cpair, csum, xb, sgb, sub, sdb, gqb, uqb, dqb);
  build_lists<<<1, 1024, 0, stream>>>(choice, cnt, tok_list, ass);

  mfma_shared_gateup<<<dim3(DFS / BN, T_TOK / BM), 256, 0, stream>>>(xb, sgb, sub, sbuf);
  mfma_expert_gateup<<<dim3(DFE / BN, T_TOK / BM, E_NUM), 256, 0, stream>>>(
      xb, gqb, uqb, gate_s, up_s, cnt, tok_list, act);
  mfma_shared_down<<<dim3(D_DIM / BN, T_TOK / BM, 2), 256, 0, stream>>>(sbuf, sdb, shd0, shd1);
  mfma_expert_down<<<dim3(D_DIM / BN, T_TOK / BM, E_NUM), 256, 0, stream>>>(
      act, dqb, down_s, cnt, pbuf);
  combine_kernel<<<T_TOK, 256, 0, stream>>>(shd0, shd1, pbuf, csum, cpair, ass, out);
}